// Round 13
// baseline (465.502 us; speedup 1.0000x reference)
//
#include <hip/hip_runtime.h>

typedef unsigned short u16;
typedef unsigned int u32;
typedef unsigned long long u64;
typedef __attribute__((ext_vector_type(8))) short bf16x8;
typedef __attribute__((ext_vector_type(4))) float f32x4;
typedef __attribute__((ext_vector_type(16))) float f32x16;

#define NEGF  -1.0e38f
#define MINIT -1.0e30f
#define LOG2E 1.4426950408889634f

__device__ __forceinline__ u16 f2bf(float x) {
  union { float f; u32 u; } v; v.f = x;
  u32 r = v.u + 0x7fffu + ((v.u >> 16) & 1u);
  return (u16)(r >> 16);
}
__device__ __forceinline__ float bf2f(u16 b) {
  union { u32 u; float f; } v; v.u = ((u32)b) << 16;
  return v.f;
}
__device__ __forceinline__ float bcast(u32 u) {
  union { u32 u; float f; } v; v.u = u; return v.f;
}
// packed f32->bf16 RNE: lo16 = cvt(a), hi16 = cvt(b)  [verified RNE: r11 absmax unchanged]
__device__ __forceinline__ u32 cvtpk(float a, float b) {
  u32 r;
  asm("v_cvt_pk_bf16_f32 %0, %1, %2" : "=v"(r) : "v"(a), "v"(b));
  return r;
}
// raw hardware exp2 (skips OCML range fixup; -huge -> 0 handled by HW)
__device__ __forceinline__ float vexp2(float x) {
  float r;
  asm("v_exp_f32 %0, %1" : "=v"(r) : "v"(x));
  return r;
}
__device__ __forceinline__ float fmax3(float a, float b, float c) {
  return fmaxf(fmaxf(a, b), c);   // clang fuses to v_max3_f32
}
__device__ __forceinline__ float leaky(float x) { return x >= 0.f ? x : 0.2f * x; }

__device__ __forceinline__ void gload16(const void* g, void* l) {
  __builtin_amdgcn_global_load_lds(
      (const __attribute__((address_space(1))) u32*)(unsigned long long)g,
      (__attribute__((address_space(3))) u32*)(u32)(unsigned long long)l,
      16, 0, 0);
}

// LDS tile geometry: 64 rows of 128B in 8 groups of 8 rows; each group skewed
// +16B (group g at byte g*1040). Each global_load_lds writes one contiguous
// 1024B group.
#define GRP   1040
#define TILE  8320            // 8 * GRP
#define KA_OFF 0
#define KB_OFF 8320
#define KC_OFF 16640
#define V_OFF  24960          // + buf*16640 + comp*8320
#define SMEM_BYTES 58240

// ---- graph [N][N] fp32 -> bitmask, CHUNK-MAJOR: bits[wd][n] (wd=kv-word 0..63) ----
__global__ __launch_bounds__(256) void pack_kernel(const float* __restrict__ graph,
                                                   u64* __restrict__ bits) {
  const int n = blockIdx.x;
  const int w = threadIdx.x >> 6, lane = threadIdx.x & 63;
  const float* gr = graph + (size_t)n * 4096;
  for (int j = 0; j < 16; ++j) {
    const int wd = j * 4 + w;
    u64 m = __ballot(gr[wd * 64 + lane] != 0.0f);
    if (lane == 0) bits[(size_t)wd * 4096 + n] = m;
  }
}

// ---- h1 = x @ Ws[h] (fp32), split-3 to bf16, FUSED transpose writes ----
// grid (64, 16): 64-row tile per (b,h). Writes h1a/b/c [16][4096][64] AND
// h1aT/bT [16][64][4096] with bit-2<->3 column swap (verified transpose path).
__global__ __launch_bounds__(256) void h1_kernel(const float* __restrict__ x,
                                                 const float* __restrict__ Ws,
                                                 u16* __restrict__ h1a, u16* __restrict__ h1b,
                                                 u16* __restrict__ h1c,
                                                 u16* __restrict__ h1aT, u16* __restrict__ h1bT) {
  const int n0 = blockIdx.x * 64;
  const int p  = blockIdx.y;                 // b*4 + h
  const int b = p >> 2, h = p & 3;
  const int t = threadIdx.x;
  const int d = t & 63, rg = t >> 6;
  __shared__ float xt[64][17];
  __shared__ u16 ta[64][66];
  __shared__ u16 tb[64][66];
  {
    const float4 v = *(const float4*)(x + ((size_t)b * 4096 + n0 + (t >> 2)) * 16 + (t & 3) * 4);
    xt[t >> 2][(t & 3) * 4 + 0] = v.x;
    xt[t >> 2][(t & 3) * 4 + 1] = v.y;
    xt[t >> 2][(t & 3) * 4 + 2] = v.z;
    xt[t >> 2][(t & 3) * 4 + 3] = v.w;
  }
  float Wd[16];
  #pragma unroll
  for (int c = 0; c < 16; ++c) Wd[c] = Ws[h * (16 * 64) + c * 64 + d];
  __syncthreads();
  #pragma unroll
  for (int it = 0; it < 16; ++it) {
    const int r = it * 4 + rg;
    float acc = 0.f;
    #pragma unroll
    for (int c = 0; c < 16; ++c) acc += xt[r][c] * Wd[c];
    const size_t o = ((size_t)p * 4096 + n0 + r) * 64 + d;
    u16 a = f2bf(acc);
    float r1 = acc - bf2f(a);
    u16 bq = f2bf(r1);
    float r2 = r1 - bf2f(bq);
    h1a[o] = a; h1b[o] = bq; h1c[o] = f2bf(r2);
    ta[r][d] = a; tb[r][d] = bq;
  }
  __syncthreads();
  const int cs = (d & 51) | ((d & 4) << 1) | ((d & 8) >> 1);  // swap bits 2,3 (n-col)
  #pragma unroll
  for (int i = 0; i < 16; ++i) {
    const int dr = i * 4 + rg;
    h1aT[((size_t)p * 64 + dr) * 4096 + n0 + cs] = ta[d][dr];
    h1bT[((size_t)p * 64 + dr) * 4096 + n0 + cs] = tb[d][dr];
  }
}

// ---- bf16 [P][4096][64] -> [P][64][4096], columns bit-2<->3 permuted ----
__global__ __launch_bounds__(256) void transpose_kernel(const u16* __restrict__ src,
                                                        u16* __restrict__ dst) {
  const int p = blockIdx.y, n0 = blockIdx.x * 64;
  const u16* s = src + (size_t)p * 4096 * 64;
  u16* d = dst + (size_t)p * 4096 * 64;
  __shared__ u16 tile[64][66];
  const int col = threadIdx.x & 63, r4 = threadIdx.x >> 6;
  #pragma unroll
  for (int i = 0; i < 16; ++i) {
    const int r = i * 4 + r4;
    tile[r][col] = s[(size_t)(n0 + r) * 64 + col];
  }
  __syncthreads();
  const int cs = (col & 51) | ((col & 4) << 1) | ((col & 8) >> 1);  // swap bits 2,3
  #pragma unroll
  for (int i = 0; i < 16; ++i) {
    const int r = i * 4 + r4;
    d[(size_t)r * 4096 + n0 + cs] = tile[col][r];
  }
}

// ---- h2 = cat @ W_out (fp32), split-3 ----
__global__ __launch_bounds__(256) void h2_kernel(const float* __restrict__ cat,
                                                 const float* __restrict__ Wout,
                                                 u16* __restrict__ h2a, u16* __restrict__ h2b,
                                                 u16* __restrict__ h2c) {
  const int row = blockIdx.x * 4 + (threadIdx.x >> 6);
  const int d = threadIdx.x & 63;
  const float* cr = cat + (size_t)row * 256;
  float acc = 0.f;
  for (int c4 = 0; c4 < 64; ++c4) {
    const float4 cv = *(const float4*)(cr + c4 * 4);
    acc += cv.x * Wout[(c4 * 4 + 0) * 64 + d];
    acc += cv.y * Wout[(c4 * 4 + 1) * 64 + d];
    acc += cv.z * Wout[(c4 * 4 + 2) * 64 + d];
    acc += cv.w * Wout[(c4 * 4 + 3) * 64 + d];
  }
  const size_t o = (size_t)row * 64 + d;
  u16 a = f2bf(acc);
  float r1 = acc - bf2f(a);
  u16 bq = f2bf(r1);
  float r2 = r1 - bf2f(bq);
  h2a[o] = a; h2b[o] = bq; h2c[o] = f2bf(r2);
}

// ---- flash attention, 32x32x16 MFMA, swapped operands (S^T / O^T) ----
// 256 threads = 4 waves, 128 q/block. K single-buffered LDS, V double-buffered LDS.
// Half-chunk online softmax: each 32-kv half runs mask/max/exp/sum/pack/PV
// independently -> PV(half0) MFMAs interleave with half1 softmax VALU.
template <int LAYER>
__global__ __launch_bounds__(256) void attn_kernel(
    const u16* __restrict__ Ha, const u16* __restrict__ Hb, const u16* __restrict__ Hc,
    const u16* __restrict__ HaT, const u16* __restrict__ HbT,
    const u64* __restrict__ bits, const float* __restrict__ bias,
    float* __restrict__ outp, float* __restrict__ pm, float* __restrict__ pl) {
  constexpr int NCH = (LAYER == 1) ? 64 : 16;
  const int orig = blockIdx.x + 32 * blockIdx.y;
  const int sid = (orig & 7) * 64 + (orig >> 3);   // bijective XCD swizzle (512 % 8 == 0)
  const int bx = sid & 31;
  const int py = sid >> 5;
  const int pass = (LAYER == 1) ? py : (py & 3);
  const int chg0 = (LAYER == 1) ? 0 : ((py >> 2) * 16);

  const int t = threadIdx.x;
  const int wq = t >> 6;           // 0..3
  const int lane = t & 63;
  const int c = lane & 31;
  const int g1 = lane >> 5;
  const int qbase = bx * 128 + wq * 32;
  const int q = qbase + c;
  const size_t poffb = (size_t)pass * (4096 * 64) * 2;

  __shared__ f32x4 smem_v[SMEM_BYTES / 16];
  char* smem = (char*)smem_v;

  const int srow = lane >> 3;
  const int scol = ((lane & 7) ^ srow) << 4;       // pre-swizzled source column
  const char* gKa = (const char*)Ha + poffb;
  const char* gKb = (const char*)Hb + poffb;
  const char* gKc = (const char*)Hc + poffb;
  const char* gVa = (const char*)HaT + poffb;
  const char* gVb = (const char*)HbT + poffb;

  // K: 64 kv-rows x 128B per comp; wave wq stages groups 2wq, 2wq+1 (6 DMAs)
  auto stageK = [&](int chg) {
    const size_t cb = (size_t)chg * 8192;
    #pragma unroll
    for (int ii = 0; ii < 2; ++ii) {
      const int g = wq * 2 + ii;
      const size_t so = cb + (size_t)(g * 8 + srow) * 128 + scol;
      const int dofs = g * GRP;
      gload16(gKa + so, smem + KA_OFF + dofs);
      gload16(gKb + so, smem + KB_OFF + dofs);
      gload16(gKc + so, smem + KC_OFF + dofs);
    }
  };
  // V: 64 d-rows x 128B per comp; wave wq stages comp wq>>1, groups (wq&1)*4..+3 (4 DMAs)
  auto stageV = [&](int chg, int buf) {
    const char* gsrc = (wq >> 1) ? gVb : gVa;
    char* dbase = smem + V_OFF + buf * 16640 + (wq >> 1) * TILE;
    const size_t cb = (size_t)chg * 128;
    #pragma unroll
    for (int ii = 0; ii < 4; ++ii) {
      const int g = (wq & 1) * 4 + ii;
      const size_t so = cb + (size_t)(g * 8 + srow) * 8192 + scol;
      gload16(gsrc + so, dbase + g * GRP);
    }
  };

  // Q B-frags: col=q=c, memory-contiguous slots (same map as K A-frags -> cancels)
  bf16x8 qf[3][4];
  {
    const char* qra = (const char*)Ha + poffb + (size_t)q * 128 + 16 * g1;
    const char* qrb = (const char*)Hb + poffb + (size_t)q * 128 + 16 * g1;
    const char* qrc = (const char*)Hc + poffb + (size_t)q * 128 + 16 * g1;
    #pragma unroll
    for (int kk = 0; kk < 4; ++kk) {
      qf[0][kk] = *(const bf16x8*)(qra + kk * 32);
      qf[1][kk] = *(const bf16x8*)(qrb + kk * 32);
      qf[2][kk] = *(const bf16x8*)(qrc + kk * 32);
    }
  }

  // chunk-major mask: bits[ch][q] -> lanes read 32 consecutive u64 (coalesced)
  const u64* bqp = bits + q;

  // frag-read byte index within a tile: row c (group c>>3 skew) + swizzled slot
  const int swz = (c & 7) << 4;
  int iK[4];
  #pragma unroll
  for (int kk = 0; kk < 4; ++kk)
    iK[kk] = c * 128 + ((c >> 3) << 4) + ((32 * kk + 16 * g1) ^ swz);

  const f32x16 z16 = {};           // persistent zero C-operand
  f32x16 Of0, Of1;
  #pragma unroll
  for (int r = 0; r < 16; ++r) { Of0[r] = 0.f; Of1[r] = 0.f; }
  float mrow = MINIT, lrow = 0.f;

  stageK(chg0);
  stageV(chg0, 0);
  u64 mcur = bqp[(size_t)chg0 * 4096];
  asm volatile("s_waitcnt vmcnt(0)" ::: "memory");
  __syncthreads();

  #pragma unroll 1
  for (int ch = 0; ch < NCH; ++ch) {
    const int chg = chg0 + ch;
    __builtin_amdgcn_sched_barrier(0);
    // ---------- S^T = K Q^T (6-term split-3, small->large), K from LDS ----------
    f32x16 s0, s1;
    __builtin_amdgcn_s_setprio(1);
    #pragma unroll
    for (int kk = 0; kk < 4; ++kk) {
      const char* kp0 = smem + iK[kk];
      const char* kp1 = smem + 4 * GRP + iK[kk];
      const bf16x8 ka0 = *(const bf16x8*)(kp0 + KA_OFF);
      const bf16x8 kb0 = *(const bf16x8*)(kp0 + KB_OFF);
      const bf16x8 kc0 = *(const bf16x8*)(kp0 + KC_OFF);
      const bf16x8 ka1 = *(const bf16x8*)(kp1 + KA_OFF);
      const bf16x8 kb1 = *(const bf16x8*)(kp1 + KB_OFF);
      const bf16x8 kc1 = *(const bf16x8*)(kp1 + KC_OFF);
      s0 = __builtin_amdgcn_mfma_f32_32x32x16_bf16(ka0, qf[2][kk], kk ? s0 : z16, 0, 0, 0);
      s1 = __builtin_amdgcn_mfma_f32_32x32x16_bf16(ka1, qf[2][kk], kk ? s1 : z16, 0, 0, 0);
      s0 = __builtin_amdgcn_mfma_f32_32x32x16_bf16(kb0, qf[1][kk], s0, 0, 0, 0);
      s1 = __builtin_amdgcn_mfma_f32_32x32x16_bf16(kb1, qf[1][kk], s1, 0, 0, 0);
      s0 = __builtin_amdgcn_mfma_f32_32x32x16_bf16(kc0, qf[0][kk], s0, 0, 0, 0);
      s1 = __builtin_amdgcn_mfma_f32_32x32x16_bf16(kc1, qf[0][kk], s1, 0, 0, 0);
      s0 = __builtin_amdgcn_mfma_f32_32x32x16_bf16(ka0, qf[1][kk], s0, 0, 0, 0);
      s1 = __builtin_amdgcn_mfma_f32_32x32x16_bf16(ka1, qf[1][kk], s1, 0, 0, 0);
      s0 = __builtin_amdgcn_mfma_f32_32x32x16_bf16(kb0, qf[0][kk], s0, 0, 0, 0);
      s1 = __builtin_amdgcn_mfma_f32_32x32x16_bf16(kb1, qf[0][kk], s1, 0, 0, 0);
      s0 = __builtin_amdgcn_mfma_f32_32x32x16_bf16(ka0, qf[0][kk], s0, 0, 0, 0);
      s1 = __builtin_amdgcn_mfma_f32_32x32x16_bf16(ka1, qf[0][kk], s1, 0, 0, 0);
    }
    __builtin_amdgcn_s_setprio(0);
    __builtin_amdgcn_sched_barrier(0);
    __builtin_amdgcn_s_barrier();                 // A: all waves done reading K/V LDS of ch
    __builtin_amdgcn_sched_barrier(0);
    if (ch + 1 < NCH) {                           // DMA next K (+ next V buf) under compute
      stageK(chg + 1);
      stageV(chg + 1, (ch + 1) & 1);
    }
    __builtin_amdgcn_sched_barrier(0);

    // ---------- two independent 32-kv half-steps: softmax+pack+PV ----------
    // (PV of half0 interleaves with half1's mask/max VALU — no dependence)
    const u32 a0 = (u32)(mcur >> (4 * g1));
    const u32 a1 = (u32)(mcur >> (32 + 4 * g1));
    const char* vbase = smem + V_OFF + (ch & 1) * 16640;
    #pragma unroll
    for (int hs = 0; hs < 2; ++hs) {
      f32x16& sm = hs ? s1 : s0;
      const u32 am = hs ? a1 : a0;
      #pragma unroll
      for (int r = 0; r < 16; ++r) {
        const int off = (r & 3) + 8 * (r >> 2);   // D row = off + 4*g1 (+32*hs)
        sm[r] = ((am >> off) & 1u) ? sm[r] : NEGF;
      }
      float t0 = fmax3(sm[0], sm[1], sm[2]);
      float t1 = fmax3(sm[3], sm[4], sm[5]);
      float t2 = fmax3(sm[6], sm[7], sm[8]);
      float t3 = fmax3(sm[9], sm[10], sm[11]);
      float t4 = fmax3(sm[12], sm[13], sm[14]);
      float mm = fmax3(fmax3(t0, t1, t2), fmaxf(t3, t4), sm[15]);
      mm = fmaxf(mm, __shfl_xor(mm, 32));
      if (!__all(mm <= mrow + 8.f)) {
        const float mn = fmaxf(mrow, mm);
        const float scl = vexp2((mrow - mn) * LOG2E);
        #pragma unroll
        for (int r = 0; r < 16; ++r) { Of0[r] *= scl; Of1[r] *= scl; }
        lrow *= scl;
        mrow = mn;
      }
      // exp: LAYER 1 FMA form (|s|~1e3, exponent err ~6e-5 harmless);
      // LAYER 2 subtract-first (|s|~1e5).
      if (LAYER == 1) {
        const float mL = mrow * LOG2E;
        #pragma unroll
        for (int r = 0; r < 16; ++r) sm[r] = vexp2(__builtin_fmaf(sm[r], LOG2E, -mL));
      } else {
        #pragma unroll
        for (int r = 0; r < 16; ++r) sm[r] = vexp2((sm[r] - mrow) * LOG2E);
      }
      {
        float r4[4];
        #pragma unroll
        for (int j = 0; j < 4; ++j)
          r4[j] = (sm[4*j] + sm[4*j+1]) + (sm[4*j+2] + sm[4*j+3]);
        float rs = (r4[0] + r4[1]) + (r4[2] + r4[3]);
        rs += __shfl_xor(rs, 32);
        lrow += rs;
      }
      // pack this half's two kk-tiles (RNE hi + RNE lo), own-lane slots
      bf16x8 pa[2], pb[2];
      #pragma unroll
      for (int k2 = 0; k2 < 2; ++k2) {
        const int rb = 8 * k2;
        union { u32 w[4]; bf16x8 v; } ua, ub;
        #pragma unroll
        for (int j = 0; j < 4; ++j) {
          const float p0 = sm[rb + 2*j], p1 = sm[rb + 2*j + 1];
          const u32 hh = cvtpk(p0, p1);
          ua.w[j] = hh;
          ub.w[j] = cvtpk(p0 - bcast(hh << 16), p1 - bcast(hh & 0xffff0000u));
        }
        pa[k2] = ua.v; pb[k2] = ub.v;
      }
      // PV for kk = 2hs+k2 (3-term split-2), interleaved Of0/Of1 chains
      __builtin_amdgcn_s_setprio(1);
      #pragma unroll
      for (int k2 = 0; k2 < 2; ++k2) {
        const int kk = 2 * hs + k2;
        const char* vp0 = vbase + iK[kk];
        const char* vp1 = vbase + 4 * GRP + iK[kk];
        const bf16x8 va0 = *(const bf16x8*)(vp0);
        const bf16x8 vb0 = *(const bf16x8*)(vp0 + TILE);
        const bf16x8 va1 = *(const bf16x8*)(vp1);
        const bf16x8 vb1 = *(const bf16x8*)(vp1 + TILE);
        Of0 = __builtin_amdgcn_mfma_f32_32x32x16_bf16(vb0, pa[k2], Of0, 0, 0, 0);
        Of1 = __builtin_amdgcn_mfma_f32_32x32x16_bf16(vb1, pa[k2], Of1, 0, 0, 0);
        Of0 = __builtin_amdgcn_mfma_f32_32x32x16_bf16(va0, pb[k2], Of0, 0, 0, 0);
        Of1 = __builtin_amdgcn_mfma_f32_32x32x16_bf16(va1, pb[k2], Of1, 0, 0, 0);
        Of0 = __builtin_amdgcn_mfma_f32_32x32x16_bf16(va0, pa[k2], Of0, 0, 0, 0);
        Of1 = __builtin_amdgcn_mfma_f32_32x32x16_bf16(va1, pa[k2], Of1, 0, 0, 0);
      }
      __builtin_amdgcn_s_setprio(0);
    }

    u64 mnxt = 0;
    if (ch + 1 < NCH) mnxt = bqp[(size_t)(chg + 1) * 4096];
    __builtin_amdgcn_sched_barrier(0);
    if (ch + 1 < NCH) {
      asm volatile("s_waitcnt vmcnt(1)" ::: "memory");   // 10 staging DMAs landed
    } else {
      asm volatile("s_waitcnt vmcnt(0)" ::: "memory");
    }
    __builtin_amdgcn_sched_barrier(0);
    __builtin_amdgcn_s_barrier();                 // B: K/V[ch+1] staged for all waves
    mcur = mnxt;
  }

  // ---------- epilogue: transpose O^T -> O via LDS, store coalesced ----------
  char* reg = smem + wq * 8704;                   // 32 q-rows x 272B (padded)
  const float inv = (LAYER == 1) ? (1.0f / lrow) : 1.0f;
  #pragma unroll
  for (int dt = 0; dt < 2; ++dt) {
    const f32x16& o = dt ? Of1 : Of0;
    #pragma unroll
    for (int i = 0; i < 4; ++i) {
      f32x4 v;
      v[0] = o[4*i+0] * inv; v[1] = o[4*i+1] * inv;
      v[2] = o[4*i+2] * inv; v[3] = o[4*i+3] * inv;
      *(f32x4*)(reg + c * 272 + (32 * dt + 8 * i + 4 * g1) * 4) = v;
    }
  }
  if (LAYER == 2 && lane < 32) {
    pm[(size_t)py * 4096 + q] = mrow;
    pl[(size_t)py * 4096 + q] = lrow;
  }
  __syncthreads();
  const int d0 = (lane & 15) * 4;
  const float* bp = (LAYER == 1) ? (bias + (pass & 3) * 64) : bias;
  #pragma unroll
  for (int qq = 0; qq < 8; ++qq) {
    const int ql = qq * 4 + (lane >> 4);
    f32x4 v = *(const f32x4*)(reg + ql * 272 + (lane & 15) * 16);
    const int qg = qbase + ql;
    if (LAYER == 1) {
      v[0] = leaky(v[0] + bp[d0 + 0]);
      v[1] = leaky(v[1] + bp[d0 + 1]);
      v[2] = leaky(v[2] + bp[d0 + 2]);
      v[3] = leaky(v[3] + bp[d0 + 3]);
      *(f32x4*)&outp[((size_t)((pass >> 2) * 4096 + qg)) * 256 + (pass & 3) * 64 + d0] = v;
    } else {
      *(f32x4*)&outp[((size_t)py * 4096 + qg) * 64 + d0] = v;
    }
  }
}

// ---- merge kv-split partials (layer 2): 4 splits x 4 passes ----
__global__ __launch_bounds__(256) void merge_kernel(
    const float* __restrict__ pO, const float* __restrict__ pm, const float* __restrict__ pl,
    const float* __restrict__ bo, float* __restrict__ dout) {
  const int t = threadIdx.x;
  const int d = t & 63;
  const int q = blockIdx.x * 4 + (t >> 6);
  const int pass = blockIdx.y;
  float m[4], l[4], o[4];
  #pragma unroll
  for (int s = 0; s < 4; ++s) {
    const size_t idx = (size_t)(s * 4 + pass) * 4096 + q;
    m[s] = pm[idx]; l[s] = pl[idx];
    o[s] = pO[idx * 64 + d];
  }
  const float M = fmaxf(fmaxf(m[0], m[1]), fmaxf(m[2], m[3]));
  float num = 0.f, den = 0.f;
  #pragma unroll
  for (int s = 0; s < 4; ++s) {
    const float w = exp2f((m[s] - M) * LOG2E);
    num += w * o[s]; den += w * l[s];
  }
  const float r = num / den + bo[d];
  dout[((size_t)pass * 4096 + q) * 64 + d] = leaky(r);
}

extern "C" void kernel_launch(void* const* d_in, const int* in_sizes, int n_in,
                              void* d_out, int out_size, void* d_ws, size_t ws_size,
                              hipStream_t stream) {
  const float* x     = (const float*)d_in[0];
  const float* graph = (const float*)d_in[1];
  const float* Ws    = (const float*)d_in[2];
  const float* bs    = (const float*)d_in[3];
  const float* W_out = (const float*)d_in[4];
  const float* b_out = (const float*)d_in[5];
  char* ws = (char*)d_ws;
  const size_t MiB = 1048576;

  u64* bits   = (u64*)(ws + 0 * MiB);      // 2 MiB [64][4096] chunk-major
  u16* h1a    = (u16*)(ws + 2 * MiB);      // 8 MiB  [16][4096][64]
  u16* h1b    = (u16*)(ws + 10 * MiB);     // 8 MiB
  u16* h1c    = (u16*)(ws + 18 * MiB);     // 8 MiB
  u16* h1aT   = (u16*)(ws + 26 * MiB);     // 8 MiB  [16][64][4096] (cols 2<->3 swapped)
  u16* h1bT   = (u16*)(ws + 34 * MiB);     // 8 MiB
  float* catb = (float*)(ws + 42 * MiB);   // 16 MiB [4][4096][256]
  u16* h2a    = (u16*)(ws + 58 * MiB);     // 2 MiB  [4][4096][64]
  u16* h2b    = (u16*)(ws + 60 * MiB);
  u16* h2c    = (u16*)(ws + 62 * MiB);
  u16* h2aT   = (u16*)(ws + 64 * MiB);
  u16* h2bT   = (u16*)(ws + 66 * MiB);
  // layer-2 partials overlay h1a/h1b/h1c (dead after attn<1>)
  float* pO   = (float*)(ws + 2 * MiB);    // 16 MiB [16][4096][64]
  float* pmb  = (float*)(ws + 18 * MiB);   // 256 KiB
  float* plb  = (float*)(ws + 18 * MiB + 262144);

  pack_kernel<<<4096, 256, 0, stream>>>(graph, bits);
  h1_kernel<<<dim3(64, 16), 256, 0, stream>>>(x, Ws, h1a, h1b, h1c, h1aT, h1bT);
  attn_kernel<1><<<dim3(32, 16), 256, 0, stream>>>(h1a, h1b, h1c, h1aT, h1bT,
                                                   bits, bs, catb, nullptr, nullptr);
  h2_kernel<<<4096, 256, 0, stream>>>(catb, W_out, h2a, h2b, h2c);
  transpose_kernel<<<dim3(64, 4), 256, 0, stream>>>(h2a, h2aT);
  transpose_kernel<<<dim3(64, 4), 256, 0, stream>>>(h2b, h2bT);
  attn_kernel<2><<<dim3(32, 16), 256, 0, stream>>>(h2a, h2b, h2c, h2aT, h2bT,
                                                   bits, b_out, pO, pmb, plb);
  merge_kernel<<<dim3(1024, 4), 256, 0, stream>>>(pO, pmb, plb, b_out, (float*)d_out);
}

// Round 14
// 436.492 us; speedup vs baseline: 1.0665x; 1.0665x over previous
//
#include <hip/hip_runtime.h>

typedef unsigned short u16;
typedef unsigned int u32;
typedef unsigned long long u64;
typedef __attribute__((ext_vector_type(8))) short bf16x8;
typedef __attribute__((ext_vector_type(4))) float f32x4;
typedef __attribute__((ext_vector_type(16))) float f32x16;

#define NEGF  -1.0e38f
#define MINIT -1.0e30f
#define LOG2E 1.4426950408889634f

__device__ __forceinline__ u16 f2bf(float x) {
  union { float f; u32 u; } v; v.f = x;
  u32 r = v.u + 0x7fffu + ((v.u >> 16) & 1u);
  return (u16)(r >> 16);
}
__device__ __forceinline__ float bf2f(u16 b) {
  union { u32 u; float f; } v; v.u = ((u32)b) << 16;
  return v.f;
}
__device__ __forceinline__ float bcast(u32 u) {
  union { u32 u; float f; } v; v.u = u; return v.f;
}
// packed f32->bf16 RNE: lo16 = cvt(a), hi16 = cvt(b)  [verified RNE: r11 absmax unchanged]
__device__ __forceinline__ u32 cvtpk(float a, float b) {
  u32 r;
  asm("v_cvt_pk_bf16_f32 %0, %1, %2" : "=v"(r) : "v"(a), "v"(b));
  return r;
}
// raw hardware exp2 (skips OCML range fixup; -huge -> 0 handled by HW)
__device__ __forceinline__ float vexp2(float x) {
  float r;
  asm("v_exp_f32 %0, %1" : "=v"(r) : "v"(x));
  return r;
}
__device__ __forceinline__ float fmax3(float a, float b, float c) {
  return fmaxf(fmaxf(a, b), c);   // clang fuses to v_max3_f32
}
__device__ __forceinline__ float leaky(float x) { return x >= 0.f ? x : 0.2f * x; }

__device__ __forceinline__ void gload16(const void* g, void* l) {
  __builtin_amdgcn_global_load_lds(
      (const __attribute__((address_space(1))) u32*)(unsigned long long)g,
      (__attribute__((address_space(3))) u32*)(u32)(unsigned long long)l,
      16, 0, 0);
}

// LDS tile geometry: 64 rows of 128B in 8 groups of 8 rows; each group skewed
// +16B (group g at byte g*1040). Each global_load_lds writes one contiguous
// 1024B group.
#define GRP   1040
#define TILE  8320            // 8 * GRP
#define KA_OFF 0
#define KB_OFF 8320
#define KC_OFF 16640
#define V_OFF  24960          // + buf*16640 + comp*8320
#define SMEM_BYTES 58240

// ---- graph [N][N] fp32 -> bitmask, CHUNK-MAJOR: bits[wd][n] (wd=kv-word 0..63) ----
__global__ __launch_bounds__(256) void pack_kernel(const float* __restrict__ graph,
                                                   u64* __restrict__ bits) {
  const int n = blockIdx.x;
  const int w = threadIdx.x >> 6, lane = threadIdx.x & 63;
  const float* gr = graph + (size_t)n * 4096;
  for (int j = 0; j < 16; ++j) {
    const int wd = j * 4 + w;
    u64 m = __ballot(gr[wd * 64 + lane] != 0.0f);
    if (lane == 0) bits[(size_t)wd * 4096 + n] = m;
  }
}

// ---- h1 = x @ Ws[h] (fp32), split-3 to bf16, FUSED transpose writes ----
// grid (64, 16): 64-row tile per (b,h). Writes h1a/b/c [16][4096][64] AND
// h1aT/bT [16][64][4096] with bit-2<->3 column swap (verified transpose path).
__global__ __launch_bounds__(256) void h1_kernel(const float* __restrict__ x,
                                                 const float* __restrict__ Ws,
                                                 u16* __restrict__ h1a, u16* __restrict__ h1b,
                                                 u16* __restrict__ h1c,
                                                 u16* __restrict__ h1aT, u16* __restrict__ h1bT) {
  const int n0 = blockIdx.x * 64;
  const int p  = blockIdx.y;                 // b*4 + h
  const int b = p >> 2, h = p & 3;
  const int t = threadIdx.x;
  const int d = t & 63, rg = t >> 6;
  __shared__ float xt[64][17];
  __shared__ u16 ta[64][66];
  __shared__ u16 tb[64][66];
  {
    const float4 v = *(const float4*)(x + ((size_t)b * 4096 + n0 + (t >> 2)) * 16 + (t & 3) * 4);
    xt[t >> 2][(t & 3) * 4 + 0] = v.x;
    xt[t >> 2][(t & 3) * 4 + 1] = v.y;
    xt[t >> 2][(t & 3) * 4 + 2] = v.z;
    xt[t >> 2][(t & 3) * 4 + 3] = v.w;
  }
  float Wd[16];
  #pragma unroll
  for (int c = 0; c < 16; ++c) Wd[c] = Ws[h * (16 * 64) + c * 64 + d];
  __syncthreads();
  #pragma unroll
  for (int it = 0; it < 16; ++it) {
    const int r = it * 4 + rg;
    float acc = 0.f;
    #pragma unroll
    for (int c = 0; c < 16; ++c) acc += xt[r][c] * Wd[c];
    const size_t o = ((size_t)p * 4096 + n0 + r) * 64 + d;
    u16 a = f2bf(acc);
    float r1 = acc - bf2f(a);
    u16 bq = f2bf(r1);
    float r2 = r1 - bf2f(bq);
    h1a[o] = a; h1b[o] = bq; h1c[o] = f2bf(r2);
    ta[r][d] = a; tb[r][d] = bq;
  }
  __syncthreads();
  const int cs = (d & 51) | ((d & 4) << 1) | ((d & 8) >> 1);  // swap bits 2,3 (n-col)
  #pragma unroll
  for (int i = 0; i < 16; ++i) {
    const int dr = i * 4 + rg;
    h1aT[((size_t)p * 64 + dr) * 4096 + n0 + cs] = ta[d][dr];
    h1bT[((size_t)p * 64 + dr) * 4096 + n0 + cs] = tb[d][dr];
  }
}

// ---- bf16 [P][4096][64] -> [P][64][4096], columns bit-2<->3 permuted ----
__global__ __launch_bounds__(256) void transpose_kernel(const u16* __restrict__ src,
                                                        u16* __restrict__ dst) {
  const int p = blockIdx.y, n0 = blockIdx.x * 64;
  const u16* s = src + (size_t)p * 4096 * 64;
  u16* d = dst + (size_t)p * 4096 * 64;
  __shared__ u16 tile[64][66];
  const int col = threadIdx.x & 63, r4 = threadIdx.x >> 6;
  #pragma unroll
  for (int i = 0; i < 16; ++i) {
    const int r = i * 4 + r4;
    tile[r][col] = s[(size_t)(n0 + r) * 64 + col];
  }
  __syncthreads();
  const int cs = (col & 51) | ((col & 4) << 1) | ((col & 8) >> 1);  // swap bits 2,3
  #pragma unroll
  for (int i = 0; i < 16; ++i) {
    const int r = i * 4 + r4;
    d[(size_t)r * 4096 + n0 + cs] = tile[col][r];
  }
}

// ---- h2 = cat @ W_out (fp32), split-3 ----
__global__ __launch_bounds__(256) void h2_kernel(const float* __restrict__ cat,
                                                 const float* __restrict__ Wout,
                                                 u16* __restrict__ h2a, u16* __restrict__ h2b,
                                                 u16* __restrict__ h2c) {
  const int row = blockIdx.x * 4 + (threadIdx.x >> 6);
  const int d = threadIdx.x & 63;
  const float* cr = cat + (size_t)row * 256;
  float acc = 0.f;
  for (int c4 = 0; c4 < 64; ++c4) {
    const float4 cv = *(const float4*)(cr + c4 * 4);
    acc += cv.x * Wout[(c4 * 4 + 0) * 64 + d];
    acc += cv.y * Wout[(c4 * 4 + 1) * 64 + d];
    acc += cv.z * Wout[(c4 * 4 + 2) * 64 + d];
    acc += cv.w * Wout[(c4 * 4 + 3) * 64 + d];
  }
  const size_t o = (size_t)row * 64 + d;
  u16 a = f2bf(acc);
  float r1 = acc - bf2f(a);
  u16 bq = f2bf(r1);
  float r2 = r1 - bf2f(bq);
  h2a[o] = a; h2b[o] = bq; h2c[o] = f2bf(r2);
}

// ---- flash attention, 32x32x16 MFMA, swapped operands (S^T / O^T) ----
// 256 threads = 4 waves, 128 q/block. K single-buffered LDS, V double-buffered LDS.
// Whole-chunk softmax (r12 structure: measured best at 300us).
template <int LAYER>
__global__ __launch_bounds__(256) void attn_kernel(
    const u16* __restrict__ Ha, const u16* __restrict__ Hb, const u16* __restrict__ Hc,
    const u16* __restrict__ HaT, const u16* __restrict__ HbT,
    const u64* __restrict__ bits, const float* __restrict__ bias,
    float* __restrict__ outp, float* __restrict__ pm, float* __restrict__ pl) {
  constexpr int NCH = (LAYER == 1) ? 64 : 16;
  const int orig = blockIdx.x + 32 * blockIdx.y;
  const int sid = (orig & 7) * 64 + (orig >> 3);   // bijective XCD swizzle (512 % 8 == 0)
  const int bx = sid & 31;
  const int py = sid >> 5;
  const int pass = (LAYER == 1) ? py : (py & 3);
  const int chg0 = (LAYER == 1) ? 0 : ((py >> 2) * 16);

  const int t = threadIdx.x;
  const int wq = t >> 6;           // 0..3
  const int lane = t & 63;
  const int c = lane & 31;
  const int g1 = lane >> 5;
  const int qbase = bx * 128 + wq * 32;
  const int q = qbase + c;
  const size_t poffb = (size_t)pass * (4096 * 64) * 2;

  __shared__ f32x4 smem_v[SMEM_BYTES / 16];
  char* smem = (char*)smem_v;

  const int srow = lane >> 3;
  const int scol = ((lane & 7) ^ srow) << 4;       // pre-swizzled source column
  const char* gKa = (const char*)Ha + poffb;
  const char* gKb = (const char*)Hb + poffb;
  const char* gKc = (const char*)Hc + poffb;
  const char* gVa = (const char*)HaT + poffb;
  const char* gVb = (const char*)HbT + poffb;

  // K: 64 kv-rows x 128B per comp; wave wq stages groups 2wq, 2wq+1 (6 DMAs)
  auto stageK = [&](int chg) {
    const size_t cb = (size_t)chg * 8192;
    #pragma unroll
    for (int ii = 0; ii < 2; ++ii) {
      const int g = wq * 2 + ii;
      const size_t so = cb + (size_t)(g * 8 + srow) * 128 + scol;
      const int dofs = g * GRP;
      gload16(gKa + so, smem + KA_OFF + dofs);
      gload16(gKb + so, smem + KB_OFF + dofs);
      gload16(gKc + so, smem + KC_OFF + dofs);
    }
  };
  // V: 64 d-rows x 128B per comp; wave wq stages comp wq>>1, groups (wq&1)*4..+3 (4 DMAs)
  auto stageV = [&](int chg, int buf) {
    const char* gsrc = (wq >> 1) ? gVb : gVa;
    char* dbase = smem + V_OFF + buf * 16640 + (wq >> 1) * TILE;
    const size_t cb = (size_t)chg * 128;
    #pragma unroll
    for (int ii = 0; ii < 4; ++ii) {
      const int g = (wq & 1) * 4 + ii;
      const size_t so = cb + (size_t)(g * 8 + srow) * 8192 + scol;
      gload16(gsrc + so, dbase + g * GRP);
    }
  };

  // Q B-frags: col=q=c, memory-contiguous slots (same map as K A-frags -> cancels)
  bf16x8 qf[3][4];
  {
    const char* qra = (const char*)Ha + poffb + (size_t)q * 128 + 16 * g1;
    const char* qrb = (const char*)Hb + poffb + (size_t)q * 128 + 16 * g1;
    const char* qrc = (const char*)Hc + poffb + (size_t)q * 128 + 16 * g1;
    #pragma unroll
    for (int kk = 0; kk < 4; ++kk) {
      qf[0][kk] = *(const bf16x8*)(qra + kk * 32);
      qf[1][kk] = *(const bf16x8*)(qrb + kk * 32);
      qf[2][kk] = *(const bf16x8*)(qrc + kk * 32);
    }
  }

  // chunk-major mask: bits[ch][q] -> lanes read 32 consecutive u64 (coalesced)
  const u64* bqp = bits + q;

  // frag-read byte index within a tile: row c (group c>>3 skew) + swizzled slot
  const int swz = (c & 7) << 4;
  int iK[4];
  #pragma unroll
  for (int kk = 0; kk < 4; ++kk)
    iK[kk] = c * 128 + ((c >> 3) << 4) + ((32 * kk + 16 * g1) ^ swz);

  const f32x16 z16 = {};           // persistent zero C-operand (kills per-chunk movs)
  f32x16 Of0, Of1;
  #pragma unroll
  for (int r = 0; r < 16; ++r) { Of0[r] = 0.f; Of1[r] = 0.f; }
  float mrow = MINIT, lrow = 0.f;

  stageK(chg0);
  stageV(chg0, 0);
  u64 mcur = bqp[(size_t)chg0 * 4096];
  asm volatile("s_waitcnt vmcnt(0)" ::: "memory");
  __syncthreads();

  #pragma unroll 1
  for (int ch = 0; ch < NCH; ++ch) {
    const int chg = chg0 + ch;
    __builtin_amdgcn_sched_barrier(0);
    // ---------- S^T = K Q^T (6-term split-3, small->large), K from LDS ----------
    // interleaved s0/s1 streams: 2 independent dependency chains at every step
    f32x16 s0, s1;
    __builtin_amdgcn_s_setprio(1);
    #pragma unroll
    for (int kk = 0; kk < 4; ++kk) {
      const char* kp0 = smem + iK[kk];
      const char* kp1 = smem + 4 * GRP + iK[kk];
      const bf16x8 ka0 = *(const bf16x8*)(kp0 + KA_OFF);
      const bf16x8 kb0 = *(const bf16x8*)(kp0 + KB_OFF);
      const bf16x8 kc0 = *(const bf16x8*)(kp0 + KC_OFF);
      const bf16x8 ka1 = *(const bf16x8*)(kp1 + KA_OFF);
      const bf16x8 kb1 = *(const bf16x8*)(kp1 + KB_OFF);
      const bf16x8 kc1 = *(const bf16x8*)(kp1 + KC_OFF);
      s0 = __builtin_amdgcn_mfma_f32_32x32x16_bf16(ka0, qf[2][kk], kk ? s0 : z16, 0, 0, 0);
      s1 = __builtin_amdgcn_mfma_f32_32x32x16_bf16(ka1, qf[2][kk], kk ? s1 : z16, 0, 0, 0);
      s0 = __builtin_amdgcn_mfma_f32_32x32x16_bf16(kb0, qf[1][kk], s0, 0, 0, 0);
      s1 = __builtin_amdgcn_mfma_f32_32x32x16_bf16(kb1, qf[1][kk], s1, 0, 0, 0);
      s0 = __builtin_amdgcn_mfma_f32_32x32x16_bf16(kc0, qf[0][kk], s0, 0, 0, 0);
      s1 = __builtin_amdgcn_mfma_f32_32x32x16_bf16(kc1, qf[0][kk], s1, 0, 0, 0);
      s0 = __builtin_amdgcn_mfma_f32_32x32x16_bf16(ka0, qf[1][kk], s0, 0, 0, 0);
      s1 = __builtin_amdgcn_mfma_f32_32x32x16_bf16(ka1, qf[1][kk], s1, 0, 0, 0);
      s0 = __builtin_amdgcn_mfma_f32_32x32x16_bf16(kb0, qf[0][kk], s0, 0, 0, 0);
      s1 = __builtin_amdgcn_mfma_f32_32x32x16_bf16(kb1, qf[0][kk], s1, 0, 0, 0);
      s0 = __builtin_amdgcn_mfma_f32_32x32x16_bf16(ka0, qf[0][kk], s0, 0, 0, 0);
      s1 = __builtin_amdgcn_mfma_f32_32x32x16_bf16(ka1, qf[0][kk], s1, 0, 0, 0);
    }
    __builtin_amdgcn_s_setprio(0);
    __builtin_amdgcn_sched_barrier(0);
    __builtin_amdgcn_s_barrier();                 // A: all waves done reading K/V LDS of ch
    __builtin_amdgcn_sched_barrier(0);
    if (ch + 1 < NCH) {                           // DMA next K (+ next V buf) under compute
      stageK(chg + 1);
      stageV(chg + 1, (ch + 1) & 1);
    }
    __builtin_amdgcn_sched_barrier(0);

    // ---------- masked online softmax (lane-local rows, defer-max) ----------
    const u32 a0 = (u32)(mcur >> (4 * g1));
    const u32 a1 = (u32)(mcur >> (32 + 4 * g1));
    #pragma unroll
    for (int r = 0; r < 16; ++r) {
      const int off = (r & 3) + 8 * (r >> 2);     // D row = off + 4*g1 (+32*mt)
      s0[r] = ((a0 >> off) & 1u) ? s0[r] : NEGF;
      s1[r] = ((a1 >> off) & 1u) ? s1[r] : NEGF;
    }
    // max over 32 values via max3 tree
    float t0 = fmax3(s0[0], s0[1], s0[2]);
    float t1 = fmax3(s0[3], s0[4], s0[5]);
    float t2 = fmax3(s0[6], s0[7], s0[8]);
    float t3 = fmax3(s0[9], s0[10], s0[11]);
    float t4 = fmax3(s0[12], s0[13], s0[14]);
    float t5 = fmax3(s0[15], s1[0], s1[1]);
    float t6 = fmax3(s1[2], s1[3], s1[4]);
    float t7 = fmax3(s1[5], s1[6], s1[7]);
    float t8 = fmax3(s1[8], s1[9], s1[10]);
    float t9 = fmax3(s1[11], s1[12], s1[13]);
    float ta = fmaxf(s1[14], s1[15]);
    float u0 = fmax3(t0, t1, t2);
    float u1 = fmax3(t3, t4, t5);
    float u2 = fmax3(t6, t7, t8);
    float u3 = fmax3(t9, ta, u0);
    float mm = fmax3(u1, u2, u3);
    mm = fmaxf(mm, __shfl_xor(mm, 32));
    if (!__all(mm <= mrow + 8.f)) {
      const float mn = fmaxf(mrow, mm);
      const float scl = vexp2((mrow - mn) * LOG2E);
      #pragma unroll
      for (int r = 0; r < 16; ++r) { Of0[r] *= scl; Of1[r] *= scl; }
      lrow *= scl;
      mrow = mn;
    }
    // exp: LAYER 1 uses FMA form (|s|~1e3 -> exponent abs err ~6e-5, harmless);
    // LAYER 2 keeps subtract-first (|s|~1e5 would give ~0.008 exponent error).
    if (LAYER == 1) {
      const float mL = mrow * LOG2E;
      #pragma unroll
      for (int r = 0; r < 16; ++r) {
        s0[r] = vexp2(__builtin_fmaf(s0[r], LOG2E, -mL));
        s1[r] = vexp2(__builtin_fmaf(s1[r], LOG2E, -mL));
      }
    } else {
      #pragma unroll
      for (int r = 0; r < 16; ++r) {
        s0[r] = vexp2((s0[r] - mrow) * LOG2E);
        s1[r] = vexp2((s1[r] - mrow) * LOG2E);
      }
    }
    {
      float r4[4];
      #pragma unroll
      for (int j = 0; j < 4; ++j)
        r4[j] = ((s0[4*j] + s0[4*j+1]) + (s0[4*j+2] + s0[4*j+3]))
              + ((s1[4*j] + s1[4*j+1]) + (s1[4*j+2] + s1[4*j+3]));
      float rs = (r4[0] + r4[1]) + (r4[2] + r4[3]);
      rs += __shfl_xor(rs, 32);
      lrow += rs;
    }

    // ---------- P -> split-2 bf16 via v_cvt_pk_bf16_f32 (RNE hi + RNE lo) ----
    bf16x8 pa[4], pb[4];
    #pragma unroll
    for (int kk = 0; kk < 4; ++kk) {
      const f32x16& sm = (kk >> 1) ? s1 : s0;
      const int rb = 8 * (kk & 1);
      union { u32 w[4]; bf16x8 v; } ua, ub;
      #pragma unroll
      for (int j = 0; j < 4; ++j) {
        const float p0 = sm[rb + 2*j], p1 = sm[rb + 2*j + 1];
        const u32 h = cvtpk(p0, p1);               // lo16=bf(p0), hi16=bf(p1)
        ua.w[j] = h;
        const float h0f = bcast(h << 16);
        const float h1f = bcast(h & 0xffff0000u);
        ub.w[j] = cvtpk(p0 - h0f, p1 - h1f);
      }
      pa[kk] = ua.v; pb[kk] = ub.v;
    }

    // ---------- O^T += V^T P^T (3-term split-2), interleaved Of0/Of1 chains ----
    const char* vbase = smem + V_OFF + (ch & 1) * 16640;
    __builtin_amdgcn_s_setprio(1);
    #pragma unroll
    for (int kk = 0; kk < 4; ++kk) {
      const char* vp0 = vbase + iK[kk];
      const char* vp1 = vbase + 4 * GRP + iK[kk];
      const bf16x8 va0 = *(const bf16x8*)(vp0);
      const bf16x8 vb0 = *(const bf16x8*)(vp0 + TILE);
      const bf16x8 va1 = *(const bf16x8*)(vp1);
      const bf16x8 vb1 = *(const bf16x8*)(vp1 + TILE);
      Of0 = __builtin_amdgcn_mfma_f32_32x32x16_bf16(vb0, pa[kk], Of0, 0, 0, 0);
      Of1 = __builtin_amdgcn_mfma_f32_32x32x16_bf16(vb1, pa[kk], Of1, 0, 0, 0);
      Of0 = __builtin_amdgcn_mfma_f32_32x32x16_bf16(va0, pb[kk], Of0, 0, 0, 0);
      Of1 = __builtin_amdgcn_mfma_f32_32x32x16_bf16(va1, pb[kk], Of1, 0, 0, 0);
      Of0 = __builtin_amdgcn_mfma_f32_32x32x16_bf16(va0, pa[kk], Of0, 0, 0, 0);
      Of1 = __builtin_amdgcn_mfma_f32_32x32x16_bf16(va1, pa[kk], Of1, 0, 0, 0);
    }
    __builtin_amdgcn_s_setprio(0);

    u64 mnxt = 0;
    if (ch + 1 < NCH) mnxt = bqp[(size_t)(chg + 1) * 4096];
    __builtin_amdgcn_sched_barrier(0);
    if (ch + 1 < NCH) {
      // 10 stage-DMAs (oldest) must land; mask load stays in flight
      asm volatile("s_waitcnt vmcnt(1)" ::: "memory");
    } else {
      asm volatile("s_waitcnt vmcnt(0)" ::: "memory");
    }
    __builtin_amdgcn_sched_barrier(0);
    __builtin_amdgcn_s_barrier();                 // B: K/V[ch+1] staged for all waves
    mcur = mnxt;
  }

  // ---------- epilogue: transpose O^T -> O via LDS, store coalesced ----------
  char* reg = smem + wq * 8704;                   // 32 q-rows x 272B (padded)
  const float inv = (LAYER == 1) ? (1.0f / lrow) : 1.0f;
  #pragma unroll
  for (int dt = 0; dt < 2; ++dt) {
    const f32x16& o = dt ? Of1 : Of0;
    #pragma unroll
    for (int i = 0; i < 4; ++i) {
      f32x4 v;
      v[0] = o[4*i+0] * inv; v[1] = o[4*i+1] * inv;
      v[2] = o[4*i+2] * inv; v[3] = o[4*i+3] * inv;
      *(f32x4*)(reg + c * 272 + (32 * dt + 8 * i + 4 * g1) * 4) = v;
    }
  }
  if (LAYER == 2 && lane < 32) {
    pm[(size_t)py * 4096 + q] = mrow;
    pl[(size_t)py * 4096 + q] = lrow;
  }
  __syncthreads();
  const int d0 = (lane & 15) * 4;
  const float* bp = (LAYER == 1) ? (bias + (pass & 3) * 64) : bias;
  #pragma unroll
  for (int qq = 0; qq < 8; ++qq) {
    const int ql = qq * 4 + (lane >> 4);
    f32x4 v = *(const f32x4*)(reg + ql * 272 + (lane & 15) * 16);
    const int qg = qbase + ql;
    if (LAYER == 1) {
      v[0] = leaky(v[0] + bp[d0 + 0]);
      v[1] = leaky(v[1] + bp[d0 + 1]);
      v[2] = leaky(v[2] + bp[d0 + 2]);
      v[3] = leaky(v[3] + bp[d0 + 3]);
      *(f32x4*)&outp[((size_t)((pass >> 2) * 4096 + qg)) * 256 + (pass & 3) * 64 + d0] = v;
    } else {
      *(f32x4*)&outp[((size_t)py * 4096 + qg) * 64 + d0] = v;
    }
  }
}

// ---- merge kv-split partials (layer 2): 4 splits x 4 passes ----
__global__ __launch_bounds__(256) void merge_kernel(
    const float* __restrict__ pO, const float* __restrict__ pm, const float* __restrict__ pl,
    const float* __restrict__ bo, float* __restrict__ dout) {
  const int t = threadIdx.x;
  const int d = t & 63;
  const int q = blockIdx.x * 4 + (t >> 6);
  const int pass = blockIdx.y;
  float m[4], l[4], o[4];
  #pragma unroll
  for (int s = 0; s < 4; ++s) {
    const size_t idx = (size_t)(s * 4 + pass) * 4096 + q;
    m[s] = pm[idx]; l[s] = pl[idx];
    o[s] = pO[idx * 64 + d];
  }
  const float M = fmaxf(fmaxf(m[0], m[1]), fmaxf(m[2], m[3]));
  float num = 0.f, den = 0.f;
  #pragma unroll
  for (int s = 0; s < 4; ++s) {
    const float w = exp2f((m[s] - M) * LOG2E);
    num += w * o[s]; den += w * l[s];
  }
  const float r = num / den + bo[d];
  dout[((size_t)pass * 4096 + q) * 64 + d] = leaky(r);
}

extern "C" void kernel_launch(void* const* d_in, const int* in_sizes, int n_in,
                              void* d_out, int out_size, void* d_ws, size_t ws_size,
                              hipStream_t stream) {
  const float* x     = (const float*)d_in[0];
  const float* graph = (const float*)d_in[1];
  const float* Ws    = (const float*)d_in[2];
  const float* bs    = (const float*)d_in[3];
  const float* W_out = (const float*)d_in[4];
  const float* b_out = (const float*)d_in[5];
  char* ws = (char*)d_ws;
  const size_t MiB = 1048576;

  u64* bits   = (u64*)(ws + 0 * MiB);      // 2 MiB [64][4096] chunk-major
  u16* h1a    = (u16*)(ws + 2 * MiB);      // 8 MiB  [16][4096][64]
  u16* h1b    = (u16*)(ws + 10 * MiB);     // 8 MiB
  u16* h1c    = (u16*)(ws + 18 * MiB);     // 8 MiB
  u16* h1aT   = (u16*)(ws + 26 * MiB);     // 8 MiB  [16][64][4096] (cols 2<->3 swapped)
  u16* h1bT   = (u16*)(ws + 34 * MiB);     // 8 MiB
  float* catb = (float*)(ws + 42 * MiB);   // 16 MiB [4][4096][256]
  u16* h2a    = (u16*)(ws + 58 * MiB);     // 2 MiB  [4][4096][64]
  u16* h2b    = (u16*)(ws + 60 * MiB);
  u16* h2c    = (u16*)(ws + 62 * MiB);
  u16* h2aT   = (u16*)(ws + 64 * MiB);
  u16* h2bT   = (u16*)(ws + 66 * MiB);
  // layer-2 partials overlay h1a/h1b/h1c (dead after attn<1>)
  float* pO   = (float*)(ws + 2 * MiB);    // 16 MiB [16][4096][64]
  float* pmb  = (float*)(ws + 18 * MiB);   // 256 KiB
  float* plb  = (float*)(ws + 18 * MiB + 262144);

  pack_kernel<<<4096, 256, 0, stream>>>(graph, bits);
  h1_kernel<<<dim3(64, 16), 256, 0, stream>>>(x, Ws, h1a, h1b, h1c, h1aT, h1bT);
  attn_kernel<1><<<dim3(32, 16), 256, 0, stream>>>(h1a, h1b, h1c, h1aT, h1bT,
                                                   bits, bs, catb, nullptr, nullptr);
  h2_kernel<<<4096, 256, 0, stream>>>(catb, W_out, h2a, h2b, h2c);
  transpose_kernel<<<dim3(64, 4), 256, 0, stream>>>(h2a, h2aT);
  transpose_kernel<<<dim3(64, 4), 256, 0, stream>>>(h2b, h2bT);
  attn_kernel<2><<<dim3(32, 16), 256, 0, stream>>>(h2a, h2b, h2c, h2aT, h2bT,
                                                   bits, b_out, pO, pmb, plb);
  merge_kernel<<<dim3(1024, 4), 256, 0, stream>>>(pO, pmb, plb, b_out, (float*)d_out);
}